// Round 9
// baseline (779.579 us; speedup 1.0000x reference)
//
#include <hip/hip_runtime.h>
#include <cstddef>

#define TPB 256
#define AB_CHUNK 4096   // edges per phase-A block

typedef __attribute__((ext_vector_type(8))) short short8;   // 8 bf16 (4 VGPRs)
typedef __attribute__((ext_vector_type(4))) float f32x4;    // MFMA C/D frag

__device__ inline unsigned short f2bf(float f) {  // RNE float->bf16
  unsigned int u = __float_as_uint(f);
  return (unsigned short)((u + 0x7fffu + ((u >> 16) & 1u)) >> 16);
}
__device__ inline float bflo(unsigned int u) { return __uint_as_float(u << 16); }
__device__ inline float bfhi(unsigned int u) { return __uint_as_float(u & 0xffff0000u); }

// ---- Phase A1: per-block coarse histogram (bucket = col>>8), LDS atomics only
__global__ __launch_bounds__(256) void histA(const int* __restrict__ col,
                                             int* __restrict__ cntmat,
                                             int E, int nbk, int nblkA) {
  __shared__ int hist[512];
  for (int i = threadIdx.x; i < nbk; i += 256) hist[i] = 0;
  __syncthreads();
  const int base = blockIdx.x * AB_CHUNK;
  const int lim  = min(base + AB_CHUNK, E);
  for (int i = base + threadIdx.x; i < lim; i += 256)
    atomicAdd(&hist[col[i] >> 8], 1);
  __syncthreads();
  for (int k = threadIdx.x; k < nbk; k += 256)
    cntmat[k * nblkA + blockIdx.x] = hist[k];   // bucket-major
}

// ---- hierarchical exclusive scan (arbitrary n; out[n] = total) ----
__global__ __launch_bounds__(256) void scan_partial(const int* __restrict__ cnt,
                                                    int* __restrict__ bsum, int n) {
  __shared__ int red[256];
  const int b = blockIdx.x, tid = threadIdx.x;
  const int base = b * 1024 + tid * 4;
  int s = 0;
  if (base + 3 < n) {
    int4 v = *(const int4*)(cnt + base);
    s = v.x + v.y + v.z + v.w;
  } else {
    for (int j = 0; j < 4; ++j) if (base + j < n) s += cnt[base + j];
  }
  red[tid] = s; __syncthreads();
  for (int off = 128; off >= 1; off >>= 1) {
    if (tid < off) red[tid] += red[tid + off];
    __syncthreads();
  }
  if (tid == 0) bsum[b] = red[0];
}

__global__ __launch_bounds__(1024) void scan_bsum(int* __restrict__ bsum, int nb,
                                                  int* __restrict__ out, int n) {
  __shared__ int sh[1024];
  const int tid = threadIdx.x;
  int v = (tid < nb) ? bsum[tid] : 0;
  sh[tid] = v; __syncthreads();
  for (int off = 1; off < 1024; off <<= 1) {
    int t = (tid >= off) ? sh[tid - off] : 0;
    __syncthreads();
    sh[tid] += t;
    __syncthreads();
  }
  if (tid < nb) bsum[tid] = sh[tid] - v;   // exclusive
  if (tid == 1023) out[n] = sh[1023];      // grand total
}

__global__ __launch_bounds__(256) void scan_apply(const int* __restrict__ cnt,
                                                  const int* __restrict__ bsum,
                                                  int* __restrict__ out, int n) {
  __shared__ int red[256];
  const int b = blockIdx.x, tid = threadIdx.x;
  const int base = b * 1024 + tid * 4;
  int v0 = 0, v1 = 0, v2 = 0, v3 = 0;
  if (base + 3 < n) {
    int4 v = *(const int4*)(cnt + base);
    v0 = v.x; v1 = v.y; v2 = v.z; v3 = v.w;
  } else {
    if (base     < n) v0 = cnt[base];
    if (base + 1 < n) v1 = cnt[base + 1];
    if (base + 2 < n) v2 = cnt[base + 2];
    if (base + 3 < n) v3 = cnt[base + 3];
  }
  const int t = v0 + v1 + v2 + v3;
  red[tid] = t; __syncthreads();
  for (int off = 1; off < 256; off <<= 1) {
    int x = (tid >= off) ? red[tid - off] : 0;
    __syncthreads();
    red[tid] += x;
    __syncthreads();
  }
  int excl = red[tid] - t + bsum[b];
  if (base     < n) out[base]     = excl;
  if (base + 1 < n) out[base + 1] = excl + v0;
  if (base + 2 < n) out[base + 2] = excl + v0 + v1;
  if (base + 3 < n) out[base + 3] = excl + v0 + v1 + v2;
}

// ---- Phase A3: scatter edges into bucket-contiguous order
// payload: {row | (col&255)<<17, w_bits}  (row < 2^17, col_local < 256)
__global__ __launch_bounds__(256) void scatA(const int* __restrict__ row,
                                             const int* __restrict__ col,
                                             const float* __restrict__ w,
                                             const int* __restrict__ scnt,
                                             int2* __restrict__ bucketed,
                                             int E, int nbk, int nblkA) {
  __shared__ int cur[512];
  for (int k = threadIdx.x; k < nbk; k += 256)
    cur[k] = scnt[k * nblkA + blockIdx.x];
  __syncthreads();
  const int base = blockIdx.x * AB_CHUNK;
  const int lim  = min(base + AB_CHUNK, E);
  for (int i = base + threadIdx.x; i < lim; i += 256) {
    int c = col[i];
    int pos = atomicAdd(&cur[c >> 8], 1);
    bucketed[pos] = make_int2(row[i] | ((c & 255) << 17), __float_as_int(w[i]));
  }
}

// ---- Phase B: per-bucket (256 nodes) local sort -> csr4 + rowptr + dinv
// csr4 entry: row(17 bits, <<15) | top-15-bits-of-bf16(w)  (w >= 0 so sign bit 0)
__global__ __launch_bounds__(256) void bucketB(const int2* __restrict__ bucketed,
                                               const int* __restrict__ scnt,
                                               unsigned int* __restrict__ csr4,
                                               int* __restrict__ rowptr,
                                               float* __restrict__ dinv,
                                               int E, int N, int nbk, int nblkA) {
  __shared__ int   hist[256];   // then reused as cursor
  __shared__ float degf[256];
  __shared__ int   excl[256];
  const int b = blockIdx.x, tid = threadIdx.x;
  const int start = scnt[b * nblkA];
  const int end   = (b == nbk - 1) ? E : scnt[(b + 1) * nblkA];
  hist[tid] = 0; degf[tid] = 0.f;
  __syncthreads();
  for (int i = start + tid; i < end; i += 256) {
    int2 p = bucketed[i];
    int cl = (p.x >> 17) & 255;
    atomicAdd(&hist[cl], 1);
    atomicAdd(&degf[cl], __int_as_float(p.y));
  }
  __syncthreads();
  const int v = hist[tid];
  excl[tid] = v;
  __syncthreads();
  for (int off = 1; off < 256; off <<= 1) {
    int t = (tid >= off) ? excl[tid - off] : 0;
    __syncthreads();
    excl[tid] += t;
    __syncthreads();
  }
  const int ex = excl[tid] - v;  // exclusive prefix within bucket
  const int node = b * 256 + tid;
  if (node < N) {
    rowptr[node] = start + ex;
    dinv[node]   = rsqrtf(degf[tid] + 1.0f);   // +1 = self-loop
  }
  if (b == nbk - 1 && tid == 0) rowptr[N] = E;
  __syncthreads();
  hist[tid] = ex;       // reuse as running cursor
  __syncthreads();
  for (int i = start + tid; i < end; i += 256) {
    int2 p = bucketed[i];
    int cl = (p.x >> 17) & 255;
    int pos = start + atomicAdd(&hist[cl], 1);
    unsigned int wq = (unsigned int)f2bf(__int_as_float(p.y)) & 0x7fffu;
    csr4[pos] = ((unsigned int)(p.x & 0x1FFFF) << 15) | wq;
  }
}

__global__ void bn_prep_kernel(const float* g1, const float* be1, const float* rm1, const float* rv1,
                               const float* g2, const float* be2, const float* rm2, const float* rv2,
                               float* sc1, float* sh1, float* sc2, float* sh2) {
  int t = threadIdx.x;
  if (t < 128) {
    float s1 = g1[t] * rsqrtf(rv1[t] + 1e-5f);
    sc1[t] = s1; sh1[t] = be1[t] - rm1[t] * s1;
    float s2 = g2[t] * rsqrtf(rv2[t] + 1e-5f);
    sc2[t] = s2; sh2[t] = be2[t] - rm2[t] * s2;
  }
}

// all three weight transposes in one launch: W[128,DOUT] f32 -> Wt[DOUT,128] bf16
__global__ void wt3_kernel(const float* __restrict__ W1, const float* __restrict__ W2,
                           const float* __restrict__ W3,
                           unsigned short* __restrict__ Wt1, unsigned short* __restrict__ Wt2,
                           unsigned short* __restrict__ Wt3) {
  int t = blockIdx.x * blockDim.x + threadIdx.x;
  if (t < 16384) {
    int nidx = t >> 7, k = t & 127;
    Wt1[t] = f2bf(W1[(size_t)k * 128 + nidx]);
  } else if (t < 32768) {
    int u = t - 16384; int nidx = u >> 7, k = u & 127;
    Wt2[u] = f2bf(W2[(size_t)k * 128 + nidx]);
  } else if (t < 40960) {
    int u = t - 32768; int nidx = u >> 7, k = u & 127;
    Wt3[u] = f2bf(W3[(size_t)k * 64 + nidx]);
  }
}

// MFMA GEMM: X[64-row tile] @ W -> y = dinv[r]*(X@W), SLICE-MAJOR packed bf16:
//   D=128: 8 slices x [n][8 uints];  D=64: 8 slices x [n][4 uints]
template<int DOUT, bool BF16IN>
__global__ __launch_bounds__(256) void gemm_mfma(
    const void* Xin,                         // f32[N,128] or slice-major hb
    const unsigned short* __restrict__ Wt,   // bf16 [DOUT][128]
    const float* __restrict__ dinv,
    unsigned int* __restrict__ XWb, int n)
{
  constexpr int CT = DOUT / 16;
  __shared__ unsigned short Xs[64][136];     // +8 pad
  __shared__ unsigned short Ws[DOUT][136];
  const int tid = threadIdx.x;
  const int r0  = blockIdx.x * 64;

  if constexpr (BF16IN) {
    // input is slice-major [8][n][8 uints] (D=128)
    const unsigned int* hbs = (const unsigned int*)Xin;
    for (int i = tid; i < 64 * 16; i += 256) {
      int rr = i >> 4, s = (i >> 1) & 7, hf = i & 1;
      uint4 v = make_uint4(0, 0, 0, 0);
      if (r0 + rr < n)
        v = *(const uint4*)(hbs + ((size_t)s * n + (r0 + rr)) * 8 + hf * 4);
      *(uint4*)(&Xs[rr][s * 16 + hf * 8]) = v;
    }
  } else {
    const float* X = (const float*)Xin;
    for (int i = tid; i < 64 * 32; i += 256) {           // float4 -> 4 bf16
      int rr = i >> 5, q = i & 31;
      float4 v = make_float4(0.f, 0.f, 0.f, 0.f);
      if (r0 + rr < n) v = *(const float4*)(X + (size_t)(r0 + rr) * 128 + q * 4);
      uint2 p;
      p.x = (unsigned)f2bf(v.x) | ((unsigned)f2bf(v.y) << 16);
      p.y = (unsigned)f2bf(v.z) | ((unsigned)f2bf(v.w) << 16);
      *(uint2*)(&Xs[rr][q * 4]) = p;
    }
  }
  for (int i = tid; i < DOUT * 16; i += 256) {
    int nr = i >> 4, q = i & 15;
    *(uint4*)(&Ws[nr][q * 8]) = *(const uint4*)(Wt + (size_t)nr * 128 + q * 8);
  }
  __syncthreads();

  const int wid  = tid >> 6, lane = tid & 63;
  const int arow = wid * 16 + (lane & 15);
  const int koff = (lane >> 4) << 3;

  short8 af[4];
#pragma unroll
  for (int s = 0; s < 4; ++s)
    af[s] = *(const short8*)(&Xs[arow][s * 32 + koff]);

  f32x4 acc[CT];
#pragma unroll
  for (int ct = 0; ct < CT; ++ct) acc[ct] = (f32x4){0.f, 0.f, 0.f, 0.f};

#pragma unroll
  for (int ct = 0; ct < CT; ++ct) {
    const int brow = ct * 16 + (lane & 15);
#pragma unroll
    for (int s = 0; s < 4; ++s) {
      short8 bf = *(const short8*)(&Ws[brow][s * 32 + koff]);
      acc[ct] = __builtin_amdgcn_mfma_f32_16x16x32_bf16(af[s], bf, acc[ct], 0, 0, 0);
    }
  }

  const int rbase = r0 + wid * 16 + ((lane >> 4) << 2);
  float dvv[4];
#pragma unroll
  for (int i = 0; i < 4; ++i) dvv[i] = (rbase + i < n) ? dinv[rbase + i] : 0.f;

#pragma unroll
  for (int ct = 0; ct < CT; ++ct) {
#pragma unroll
    for (int i = 0; i < 4; ++i) {
      float v = acc[ct][i] * dvv[i];
      float o = __shfl_xor(v, 1);   // partner col
      if (!(lane & 1) && rbase + i < n) {
        unsigned int p = (unsigned)f2bf(v) | ((unsigned)f2bf(o) << 16);
        int cp = ct * 8 + ((lane & 15) >> 1);           // uint-pair column
        if constexpr (DOUT == 128)
          XWb[((size_t)(cp >> 3) * n + (rbase + i)) * 8 + (cp & 7)] = p;
        else
          XWb[((size_t)(cp >> 2) * n + (rbase + i)) * 4 + (cp & 3)] = p;
      }
    }
  }
}

// slice-partitioned pull-gather. slice = blockIdx % 8 (XCD round-robin -> each
// XCD's L2 only holds its 1/8 feature slice of xwb).
// SLICE_U = uints per node per slice (8 -> 16 feats, 4 -> 8 feats).
// MODE 0: + bias, BN, ReLU -> slice-major packed bf16 hb.
// MODE 1: + bias -> slice-major f32 h3 + per-slice sumsq psum (normalize later).
template<int SLICE_U, int MODE>
__global__ __launch_bounds__(256) void gather_kernel(
    const int* __restrict__ rowptr, const unsigned int* __restrict__ csr4,
    const unsigned int* __restrict__ xwbs, const float* __restrict__ dinv,
    const float* __restrict__ bias,
    const float* __restrict__ bnsc, const float* __restrict__ bnsh,
    void* __restrict__ outp, float* __restrict__ psum, int n)
{
  const int slice = blockIdx.x & 7;
  const int node  = (int)(blockIdx.x >> 3) * 4 + (int)(threadIdx.x >> 6);
  const int lane  = threadIdx.x & 63;
  if (node >= n) return;
  const int start = rowptr[node];
  const int end   = rowptr[node + 1];
  const float dv  = dinv[node];
  constexpr int LPE   = SLICE_U / 2;     // lanes per edge (uint2 each)
  constexpr int NSLOT = 64 / LPE;        // edges in flight per wave
  const int li = lane & (LPE - 1);
  const int es = lane / LPE;
  const unsigned int* base = xwbs + (size_t)slice * n * SLICE_U;

  float a0 = 0.f, a1 = 0.f, a2 = 0.f, a3 = 0.f;
  for (int e = start; e < end; e += NSLOT) {
    int idx = e + es;
    bool valid = idx < end;
    unsigned int c = csr4[valid ? idx : start];
    int r = (int)(c >> 15);
    float nm = valid ? __uint_as_float((c & 0x7fffu) << 16) : 0.f;
    uint2 u = *(const uint2*)(base + (size_t)r * SLICE_U + li * 2);
    a0 = fmaf(bflo(u.x), nm, a0); a1 = fmaf(bfhi(u.x), nm, a1);
    a2 = fmaf(bflo(u.y), nm, a2); a3 = fmaf(bfhi(u.y), nm, a3);
  }
  // butterfly-reduce over edge slots
#pragma unroll
  for (int off = LPE; off < 64; off <<= 1) {
    a0 += __shfl_xor(a0, off); a1 += __shfl_xor(a1, off);
    a2 += __shfl_xor(a2, off); a3 += __shfl_xor(a3, off);
  }
  // self term
  uint2 su = *(const uint2*)(base + (size_t)node * SLICE_U + li * 2);
  a0 += bflo(su.x); a1 += bfhi(su.x); a2 += bflo(su.y); a3 += bfhi(su.y);
  const int f = slice * (SLICE_U * 2) + li * 4;
  a0 = fmaf(dv, a0, bias[f]);     a1 = fmaf(dv, a1, bias[f + 1]);
  a2 = fmaf(dv, a2, bias[f + 2]); a3 = fmaf(dv, a3, bias[f + 3]);

  if constexpr (MODE == 0) {
    a0 = fmaxf(fmaf(a0, bnsc[f],     bnsh[f]),     0.f);
    a1 = fmaxf(fmaf(a1, bnsc[f + 1], bnsh[f + 1]), 0.f);
    a2 = fmaxf(fmaf(a2, bnsc[f + 2], bnsh[f + 2]), 0.f);
    a3 = fmaxf(fmaf(a3, bnsc[f + 3], bnsh[f + 3]), 0.f);
    if (es == 0) {
      uint2 p;
      p.x = (unsigned)f2bf(a0) | ((unsigned)f2bf(a1) << 16);
      p.y = (unsigned)f2bf(a2) | ((unsigned)f2bf(a3) << 16);
      *(uint2*)((unsigned int*)outp + ((size_t)slice * n + node) * SLICE_U + li * 2) = p;
    }
  } else {
    float s = a0 * a0 + a1 * a1 + a2 * a2 + a3 * a3;
    s += __shfl_xor(s, 1);        // sum over the 2 li halves (LPE == 2)
    if (lane == 0) psum[(size_t)slice * n + node] = s;
    if (es == 0) {
      float4 o = make_float4(a0, a1, a2, a3);
      *(float4*)((float*)outp + ((size_t)slice * n + node) * 8 + li * 4) = o;
    }
  }
}

// final normalize: out[node][64] = h3 / max(||.||, eps); h3 slice-major [8][n][8]
__global__ __launch_bounds__(256) void norm_kernel(const float* __restrict__ h3,
                                                   const float* __restrict__ psum,
                                                   float* __restrict__ out, int n) {
  int t = blockIdx.x * 256 + threadIdx.x;
  int node = t >> 6, lane = t & 63;
  if (node >= n) return;
  float part = psum[(size_t)(lane & 7) * n + node];
  part += __shfl_xor(part, 1);
  part += __shfl_xor(part, 2);
  part += __shfl_xor(part, 4);   // each 8-lane group now holds total sumsq
  int slice = lane >> 3, f = lane & 7;
  float v = h3[((size_t)slice * n + node) * 8 + f];
  out[(size_t)node * 64 + lane] = v / fmaxf(sqrtf(part), 1e-12f);
}

extern "C" void kernel_launch(void* const* d_in, const int* in_sizes, int n_in,
                              void* d_out, int out_size, void* d_ws, size_t ws_size,
                              hipStream_t stream)
{
  const float* x   = (const float*)d_in[0];
  const int*   ei  = (const int*)d_in[1];
  const float* ew  = (const float*)d_in[2];
  const float* W1  = (const float*)d_in[3];
  const float* b1  = (const float*)d_in[4];
  const float* g1  = (const float*)d_in[5];
  const float* be1 = (const float*)d_in[6];
  const float* rm1 = (const float*)d_in[7];
  const float* rv1 = (const float*)d_in[8];
  const float* W2  = (const float*)d_in[9];
  const float* b2  = (const float*)d_in[10];
  const float* g2  = (const float*)d_in[11];
  const float* be2 = (const float*)d_in[12];
  const float* rm2 = (const float*)d_in[13];
  const float* rv2 = (const float*)d_in[14];
  const float* W3  = (const float*)d_in[15];
  const float* b3  = (const float*)d_in[16];

  const int N = in_sizes[0] / 128;
  const int E = in_sizes[2];
  const int* row = ei;       // edge_index[0]
  const int* col = ei + E;   // edge_index[1]

  const int nbk   = (N + 255) >> 8;                 // coarse buckets (col>>8)
  const int nblkA = (E + AB_CHUNK - 1) / AB_CHUNK;  // phase-A blocks
  const int L     = nbk * nblkA;                    // count-matrix length
  const int nb2   = (L + 1023) / 1024;              // scan partial blocks

  char* ws = (char*)d_ws;
  size_t off = 0;
  auto alloc = [&](size_t bytes) -> void* {
    void* p = ws + off;
    off += (bytes + 255) & ~(size_t)255;
    return p;
  };
  int*   cntmat = (int*)  alloc((size_t)L * 4);
  int*   scnt   = (int*)  alloc((size_t)(L + 1) * 4);
  int*   bsum   = (int*)  alloc((size_t)1024 * 4);
  int2*  bucketed = (int2*)alloc((size_t)E * 8);
  unsigned int* csr4 = (unsigned int*)alloc((size_t)E * 4);
  int*   rowptr = (int*)  alloc((size_t)(N + 1) * 4);
  float* dinv   = (float*)alloc((size_t)N * 4);
  float* sc1    = (float*)alloc(512);
  float* sh1    = (float*)alloc(512);
  float* sc2    = (float*)alloc(512);
  float* sh2    = (float*)alloc(512);
  unsigned short* Wt1 = (unsigned short*)alloc(128 * 128 * 2);
  unsigned short* Wt2 = (unsigned short*)alloc(128 * 128 * 2);
  unsigned short* Wt3 = (unsigned short*)alloc(64 * 128 * 2);
  unsigned int* xwb = (unsigned int*)alloc((size_t)N * 64 * 4);  // slice-major y
  unsigned int* hb  = (unsigned int*)alloc((size_t)N * 64 * 4);  // slice-major h
  float* h3   = (float*)alloc((size_t)N * 64 * 4);               // slice-major final (f32)
  float* psum = (float*)alloc((size_t)N * 8 * 4);                // per-slice sumsq

  // ---- weight transposes + BN prep ----
  wt3_kernel<<<160, 256, 0, stream>>>(W1, W2, W3, Wt1, Wt2, Wt3);
  bn_prep_kernel<<<1, 128, 0, stream>>>(g1, be1, rm1, rv1, g2, be2, rm2, rv2,
                                        sc1, sh1, sc2, sh2);

  // ---- CSR build (deterministic two-level bucket sort) ----
  histA<<<nblkA, 256, 0, stream>>>(col, cntmat, E, nbk, nblkA);
  scan_partial<<<nb2, 256, 0, stream>>>(cntmat, bsum, L);
  scan_bsum<<<1, 1024, 0, stream>>>(bsum, nb2, scnt, L);
  scan_apply<<<nb2, 256, 0, stream>>>(cntmat, bsum, scnt, L);
  scatA<<<nblkA, 256, 0, stream>>>(row, col, ew, scnt, bucketed, E, nbk, nblkA);
  bucketB<<<nbk, 256, 0, stream>>>(bucketed, scnt, csr4, rowptr, dinv, E, N, nbk, nblkA);

  const int gGM = (N + 63) / 64;          // mfma gemm blocks (64 rows each)
  const int gW  = ((N + 3) / 4) * 8;      // gather blocks: nodeBlocks x 8 slices
  const int gNm = (N * 64 + 255) / 256;   // normalize blocks

  // layer 1
  gemm_mfma<128, false><<<gGM, 256, 0, stream>>>(x, Wt1, dinv, xwb, N);
  gather_kernel<8, 0><<<gW, 256, 0, stream>>>(rowptr, csr4, xwb, dinv, b1, sc1, sh1, hb, nullptr, N);

  // layer 2
  gemm_mfma<128, true><<<gGM, 256, 0, stream>>>(hb, Wt2, dinv, xwb, N);
  gather_kernel<8, 0><<<gW, 256, 0, stream>>>(rowptr, csr4, xwb, dinv, b2, sc2, sh2, hb, nullptr, N);

  // layer 3 (DOUT=64) -> unnormalized h3 + psum, then normalize -> d_out
  gemm_mfma<64, true><<<gGM, 256, 0, stream>>>(hb, Wt3, dinv, xwb, N);
  gather_kernel<4, 1><<<gW, 256, 0, stream>>>(rowptr, csr4, xwb, dinv, b3, nullptr, nullptr, h3, psum, N);
  norm_kernel<<<gNm, 256, 0, stream>>>(h3, psum, (float*)d_out, N);
}

// Round 10
// 329.759 us; speedup vs baseline: 2.3641x; 2.3641x over previous
//
#include <hip/hip_runtime.h>
#include <cstddef>

#define TPB 256
#define AB_CHUNK 4096   // edges per phase-A block

typedef __attribute__((ext_vector_type(8))) short short8;   // 8 bf16 (4 VGPRs)
typedef __attribute__((ext_vector_type(4))) float f32x4;    // MFMA C/D frag

__device__ inline unsigned short f2bf(float f) {  // RNE float->bf16
  unsigned int u = __float_as_uint(f);
  return (unsigned short)((u + 0x7fffu + ((u >> 16) & 1u)) >> 16);
}
__device__ inline float bflo(unsigned int u) { return __uint_as_float(u << 16); }
__device__ inline float bfhi(unsigned int u) { return __uint_as_float(u & 0xffff0000u); }

// decode csr4 entry: row(17 bits, <<15) | top-15-bits-of-bf16(w)
__device__ inline int   c4row(unsigned int c) { return (int)(c >> 15); }
__device__ inline float c4w(unsigned int c)   { return __uint_as_float((c & 0x7fffu) << 16); }

// ---- Phase A1: per-block coarse histogram (bucket = col>>8), LDS atomics only
__global__ __launch_bounds__(256) void histA(const int* __restrict__ col,
                                             int* __restrict__ cntmat,
                                             int E, int nbk, int nblkA) {
  __shared__ int hist[512];
  for (int i = threadIdx.x; i < nbk; i += 256) hist[i] = 0;
  __syncthreads();
  const int base = blockIdx.x * AB_CHUNK;
  const int lim  = min(base + AB_CHUNK, E);
  for (int i = base + threadIdx.x; i < lim; i += 256)
    atomicAdd(&hist[col[i] >> 8], 1);
  __syncthreads();
  for (int k = threadIdx.x; k < nbk; k += 256)
    cntmat[k * nblkA + blockIdx.x] = hist[k];   // bucket-major
}

// ---- hierarchical exclusive scan (arbitrary n; out[n] = total) ----
__global__ __launch_bounds__(256) void scan_partial(const int* __restrict__ cnt,
                                                    int* __restrict__ bsum, int n) {
  __shared__ int red[256];
  const int b = blockIdx.x, tid = threadIdx.x;
  const int base = b * 1024 + tid * 4;
  int s = 0;
  if (base + 3 < n) {
    int4 v = *(const int4*)(cnt + base);
    s = v.x + v.y + v.z + v.w;
  } else {
    for (int j = 0; j < 4; ++j) if (base + j < n) s += cnt[base + j];
  }
  red[tid] = s; __syncthreads();
  for (int off = 128; off >= 1; off >>= 1) {
    if (tid < off) red[tid] += red[tid + off];
    __syncthreads();
  }
  if (tid == 0) bsum[b] = red[0];
}

__global__ __launch_bounds__(1024) void scan_bsum(int* __restrict__ bsum, int nb,
                                                  int* __restrict__ out, int n) {
  __shared__ int sh[1024];
  const int tid = threadIdx.x;
  int v = (tid < nb) ? bsum[tid] : 0;
  sh[tid] = v; __syncthreads();
  for (int off = 1; off < 1024; off <<= 1) {
    int t = (tid >= off) ? sh[tid - off] : 0;
    __syncthreads();
    sh[tid] += t;
    __syncthreads();
  }
  if (tid < nb) bsum[tid] = sh[tid] - v;   // exclusive
  if (tid == 1023) out[n] = sh[1023];      // grand total
}

__global__ __launch_bounds__(256) void scan_apply(const int* __restrict__ cnt,
                                                  const int* __restrict__ bsum,
                                                  int* __restrict__ out, int n) {
  __shared__ int red[256];
  const int b = blockIdx.x, tid = threadIdx.x;
  const int base = b * 1024 + tid * 4;
  int v0 = 0, v1 = 0, v2 = 0, v3 = 0;
  if (base + 3 < n) {
    int4 v = *(const int4*)(cnt + base);
    v0 = v.x; v1 = v.y; v2 = v.z; v3 = v.w;
  } else {
    if (base     < n) v0 = cnt[base];
    if (base + 1 < n) v1 = cnt[base + 1];
    if (base + 2 < n) v2 = cnt[base + 2];
    if (base + 3 < n) v3 = cnt[base + 3];
  }
  const int t = v0 + v1 + v2 + v3;
  red[tid] = t; __syncthreads();
  for (int off = 1; off < 256; off <<= 1) {
    int x = (tid >= off) ? red[tid - off] : 0;
    __syncthreads();
    red[tid] += x;
    __syncthreads();
  }
  int excl = red[tid] - t + bsum[b];
  if (base     < n) out[base]     = excl;
  if (base + 1 < n) out[base + 1] = excl + v0;
  if (base + 2 < n) out[base + 2] = excl + v0 + v1;
  if (base + 3 < n) out[base + 3] = excl + v0 + v1 + v2;
}

// ---- Phase A3: scatter edges into bucket-contiguous order
// payload: {row | (col&255)<<17, w_bits}  (row < 2^17, col_local < 256)
__global__ __launch_bounds__(256) void scatA(const int* __restrict__ row,
                                             const int* __restrict__ col,
                                             const float* __restrict__ w,
                                             const int* __restrict__ scnt,
                                             int2* __restrict__ bucketed,
                                             int E, int nbk, int nblkA) {
  __shared__ int cur[512];
  for (int k = threadIdx.x; k < nbk; k += 256)
    cur[k] = scnt[k * nblkA + blockIdx.x];
  __syncthreads();
  const int base = blockIdx.x * AB_CHUNK;
  const int lim  = min(base + AB_CHUNK, E);
  for (int i = base + threadIdx.x; i < lim; i += 256) {
    int c = col[i];
    int pos = atomicAdd(&cur[c >> 8], 1);
    bucketed[pos] = make_int2(row[i] | ((c & 255) << 17), __float_as_int(w[i]));
  }
}

// ---- Phase B: per-bucket (256 nodes) local sort -> csr4 + rowptr + dinv
__global__ __launch_bounds__(256) void bucketB(const int2* __restrict__ bucketed,
                                               const int* __restrict__ scnt,
                                               unsigned int* __restrict__ csr4,
                                               int* __restrict__ rowptr,
                                               float* __restrict__ dinv,
                                               int E, int N, int nbk, int nblkA) {
  __shared__ int   hist[256];   // then reused as cursor
  __shared__ float degf[256];
  __shared__ int   excl[256];
  const int b = blockIdx.x, tid = threadIdx.x;
  const int start = scnt[b * nblkA];
  const int end   = (b == nbk - 1) ? E : scnt[(b + 1) * nblkA];
  hist[tid] = 0; degf[tid] = 0.f;
  __syncthreads();
  for (int i = start + tid; i < end; i += 256) {
    int2 p = bucketed[i];
    int cl = (p.x >> 17) & 255;
    atomicAdd(&hist[cl], 1);
    atomicAdd(&degf[cl], __int_as_float(p.y));
  }
  __syncthreads();
  const int v = hist[tid];
  excl[tid] = v;
  __syncthreads();
  for (int off = 1; off < 256; off <<= 1) {
    int t = (tid >= off) ? excl[tid - off] : 0;
    __syncthreads();
    excl[tid] += t;
    __syncthreads();
  }
  const int ex = excl[tid] - v;  // exclusive prefix within bucket
  const int node = b * 256 + tid;
  if (node < N) {
    rowptr[node] = start + ex;
    dinv[node]   = rsqrtf(degf[tid] + 1.0f);   // +1 = self-loop
  }
  if (b == nbk - 1 && tid == 0) rowptr[N] = E;
  __syncthreads();
  hist[tid] = ex;       // reuse as running cursor
  __syncthreads();
  for (int i = start + tid; i < end; i += 256) {
    int2 p = bucketed[i];
    int cl = (p.x >> 17) & 255;
    int pos = start + atomicAdd(&hist[cl], 1);
    unsigned int wq = (unsigned int)f2bf(__int_as_float(p.y)) & 0x7fffu;
    csr4[pos] = ((unsigned int)(p.x & 0x1FFFF) << 15) | wq;   // {row, bf16 w}
  }
}

__global__ void bn_prep_kernel(const float* g1, const float* be1, const float* rm1, const float* rv1,
                               const float* g2, const float* be2, const float* rm2, const float* rv2,
                               float* sc1, float* sh1, float* sc2, float* sh2) {
  int t = threadIdx.x;
  if (t < 128) {
    float s1 = g1[t] * rsqrtf(rv1[t] + 1e-5f);
    sc1[t] = s1; sh1[t] = be1[t] - rm1[t] * s1;
    float s2 = g2[t] * rsqrtf(rv2[t] + 1e-5f);
    sc2[t] = s2; sh2[t] = be2[t] - rm2[t] * s2;
  }
}

// all three weight transposes in one launch: W[128,DOUT] f32 -> Wt[DOUT,128] bf16
__global__ void wt3_kernel(const float* __restrict__ W1, const float* __restrict__ W2,
                           const float* __restrict__ W3,
                           unsigned short* __restrict__ Wt1, unsigned short* __restrict__ Wt2,
                           unsigned short* __restrict__ Wt3) {
  int t = blockIdx.x * blockDim.x + threadIdx.x;
  if (t < 16384) {
    int nidx = t >> 7, k = t & 127;
    Wt1[t] = f2bf(W1[(size_t)k * 128 + nidx]);
  } else if (t < 32768) {
    int u = t - 16384; int nidx = u >> 7, k = u & 127;
    Wt2[u] = f2bf(W2[(size_t)k * 128 + nidx]);
  } else if (t < 40960) {
    int u = t - 32768; int nidx = u >> 7, k = u & 127;
    Wt3[u] = f2bf(W3[(size_t)k * 64 + nidx]);
  }
}

// MFMA GEMM: Xbf[64-row tile] @ W -> y = dinv[r]*(X@W) packed bf16 (ld = DOUT/2 uints)
template<int DOUT, bool BF16IN>
__global__ __launch_bounds__(256) void gemm_mfma(
    const void* Xin,                         // f32[N,128] or packed-bf16 uint[N,64]
    const unsigned short* __restrict__ Wt,   // bf16 [DOUT][128]
    const float* __restrict__ dinv,
    unsigned int* __restrict__ XWb, int n)
{
  constexpr int CT = DOUT / 16;
  __shared__ unsigned short Xs[64][136];     // +8 pad: 2-way banks (free)
  __shared__ unsigned short Ws[DOUT][136];
  const int tid = threadIdx.x;
  const int r0  = blockIdx.x * 64;

  if constexpr (BF16IN) {
    const unsigned int* hb = (const unsigned int*)Xin;
    for (int i = tid; i < 64 * 16; i += 256) {           // uint4 = 8 bf16
      int rr = i >> 4, q = i & 15;
      uint4 v = make_uint4(0, 0, 0, 0);
      if (r0 + rr < n) v = *(const uint4*)(hb + (size_t)(r0 + rr) * 64 + q * 4);
      *(uint4*)(&Xs[rr][q * 8]) = v;
    }
  } else {
    const float* X = (const float*)Xin;
    for (int i = tid; i < 64 * 32; i += 256) {           // float4 -> 4 bf16
      int rr = i >> 5, q = i & 31;
      float4 v = make_float4(0.f, 0.f, 0.f, 0.f);
      if (r0 + rr < n) v = *(const float4*)(X + (size_t)(r0 + rr) * 128 + q * 4);
      uint2 p;
      p.x = (unsigned)f2bf(v.x) | ((unsigned)f2bf(v.y) << 16);
      p.y = (unsigned)f2bf(v.z) | ((unsigned)f2bf(v.w) << 16);
      *(uint2*)(&Xs[rr][q * 4]) = p;
    }
  }
  for (int i = tid; i < DOUT * 16; i += 256) {
    int nr = i >> 4, q = i & 15;
    *(uint4*)(&Ws[nr][q * 8]) = *(const uint4*)(Wt + (size_t)nr * 128 + q * 8);
  }
  __syncthreads();

  const int wid  = tid >> 6, lane = tid & 63;
  const int arow = wid * 16 + (lane & 15);
  const int koff = (lane >> 4) << 3;

  short8 af[4];
#pragma unroll
  for (int s = 0; s < 4; ++s)
    af[s] = *(const short8*)(&Xs[arow][s * 32 + koff]);

  f32x4 acc[CT];
#pragma unroll
  for (int ct = 0; ct < CT; ++ct) acc[ct] = (f32x4){0.f, 0.f, 0.f, 0.f};

#pragma unroll
  for (int ct = 0; ct < CT; ++ct) {
    const int brow = ct * 16 + (lane & 15);
#pragma unroll
    for (int s = 0; s < 4; ++s) {
      short8 bf = *(const short8*)(&Ws[brow][s * 32 + koff]);
      acc[ct] = __builtin_amdgcn_mfma_f32_16x16x32_bf16(af[s], bf, acc[ct], 0, 0, 0);
    }
  }

  const int rbase = r0 + wid * 16 + ((lane >> 4) << 2);
  float dvv[4];
#pragma unroll
  for (int i = 0; i < 4; ++i) dvv[i] = (rbase + i < n) ? dinv[rbase + i] : 0.f;

#pragma unroll
  for (int ct = 0; ct < CT; ++ct) {
#pragma unroll
    for (int i = 0; i < 4; ++i) {
      float v = acc[ct][i] * dvv[i];
      float o = __shfl_xor(v, 1);   // partner col
      if (!(lane & 1) && rbase + i < n) {
        unsigned int p = (unsigned)f2bf(v) | ((unsigned)f2bf(o) << 16);
        XWb[(size_t)(rbase + i) * (DOUT / 2) + ct * 8 + ((lane & 15) >> 1)] = p;
      }
    }
  }
}

// unpack-accumulate a uint4 (8 bf16) scaled by nm into a0..a7
#define ACC8(u, nm)                                                   \
  a0 = fmaf(bflo((u).x), (nm), a0); a1 = fmaf(bfhi((u).x), (nm), a1); \
  a2 = fmaf(bflo((u).y), (nm), a2); a3 = fmaf(bfhi((u).y), (nm), a3); \
  a4 = fmaf(bflo((u).z), (nm), a4); a5 = fmaf(bfhi((u).z), (nm), a5); \
  a6 = fmaf(bflo((u).w), (nm), a6); a7 = fmaf(bfhi((u).w), (nm), a7);

// pull-gather from bf16 y: h = bias + dinv[i]*( y_i + sum_e w_e * y_{row_e} )
// MODE 0 (D=128): 16 lanes x uint4 per edge, 4 edge slots, 16 edges in flight;
//                 BN+ReLU fused, writes packed bf16.
// MODE 1 (D=64):  8 lanes x uint4 per edge, 8 edge slots;
//                 L2-normalize fused, writes f32 d_out.
template<int MODE>
__global__ __launch_bounds__(256) void gather_kernel(
    const int* __restrict__ rowptr, const unsigned int* __restrict__ csr4,
    const unsigned int* __restrict__ xwb, const float* __restrict__ dinv,
    const float* __restrict__ bias,
    const float* __restrict__ bnsc, const float* __restrict__ bnsh,
    void* __restrict__ outp, int n)
{
  int wid  = (blockIdx.x * blockDim.x + threadIdx.x) >> 6;
  int lane = threadIdx.x & 63;
  if (wid >= n) return;
  const int start = rowptr[wid];
  const int end   = rowptr[wid + 1];
  const float dv  = dinv[wid];
  float a0 = 0.f, a1 = 0.f, a2 = 0.f, a3 = 0.f;
  float a4 = 0.f, a5 = 0.f, a6 = 0.f, a7 = 0.f;

  if constexpr (MODE == 0) {
    const int li = lane & 15;   // uint4 index: features 8*li .. 8*li+7
    const int es = lane >> 4;   // edge slot (0..3)
    int e = start;
    for (; e + 15 < end; e += 16) {
      unsigned int c0 = csr4[e      + es], c1 = csr4[e + 4  + es];
      unsigned int c2 = csr4[e + 8  + es], c3 = csr4[e + 12 + es];
      uint4 u0 = ((const uint4*)(xwb + (size_t)c4row(c0) * 64))[li];
      uint4 u1 = ((const uint4*)(xwb + (size_t)c4row(c1) * 64))[li];
      uint4 u2 = ((const uint4*)(xwb + (size_t)c4row(c2) * 64))[li];
      uint4 u3 = ((const uint4*)(xwb + (size_t)c4row(c3) * 64))[li];
      float n0 = c4w(c0), n1 = c4w(c1), n2 = c4w(c2), n3 = c4w(c3);
      ACC8(u0, n0); ACC8(u1, n1); ACC8(u2, n2); ACC8(u3, n3);
    }
    for (; e + 3 < end; e += 4) {
      unsigned int c0 = csr4[e + es];
      uint4 u0 = ((const uint4*)(xwb + (size_t)c4row(c0) * 64))[li];
      ACC8(u0, c4w(c0));
    }
    for (; e < end; ++e) {
      unsigned int c0 = csr4[e];
      uint4 u0 = ((const uint4*)(xwb + (size_t)c4row(c0) * 64))[li];
      float n0 = (es == 0) ? c4w(c0) : 0.f;
      ACC8(u0, n0);
    }
    // reduce the four edge slots
    a0 += __shfl_xor(a0, 16); a1 += __shfl_xor(a1, 16);
    a2 += __shfl_xor(a2, 16); a3 += __shfl_xor(a3, 16);
    a4 += __shfl_xor(a4, 16); a5 += __shfl_xor(a5, 16);
    a6 += __shfl_xor(a6, 16); a7 += __shfl_xor(a7, 16);
    a0 += __shfl_xor(a0, 32); a1 += __shfl_xor(a1, 32);
    a2 += __shfl_xor(a2, 32); a3 += __shfl_xor(a3, 32);
    a4 += __shfl_xor(a4, 32); a5 += __shfl_xor(a5, 32);
    a6 += __shfl_xor(a6, 32); a7 += __shfl_xor(a7, 32);
    // self + dinv + bias + BN + ReLU
    uint4 su = ((const uint4*)(xwb + (size_t)wid * 64))[li];
    a0 += bflo(su.x); a1 += bfhi(su.x); a2 += bflo(su.y); a3 += bfhi(su.y);
    a4 += bflo(su.z); a5 += bfhi(su.z); a6 += bflo(su.w); a7 += bfhi(su.w);
    const int f = li * 8;
    a0 = fmaf(dv, a0, bias[f]);     a1 = fmaf(dv, a1, bias[f + 1]);
    a2 = fmaf(dv, a2, bias[f + 2]); a3 = fmaf(dv, a3, bias[f + 3]);
    a4 = fmaf(dv, a4, bias[f + 4]); a5 = fmaf(dv, a5, bias[f + 5]);
    a6 = fmaf(dv, a6, bias[f + 6]); a7 = fmaf(dv, a7, bias[f + 7]);
    a0 = fmaxf(fmaf(a0, bnsc[f],     bnsh[f]),     0.f);
    a1 = fmaxf(fmaf(a1, bnsc[f + 1], bnsh[f + 1]), 0.f);
    a2 = fmaxf(fmaf(a2, bnsc[f + 2], bnsh[f + 2]), 0.f);
    a3 = fmaxf(fmaf(a3, bnsc[f + 3], bnsh[f + 3]), 0.f);
    a4 = fmaxf(fmaf(a4, bnsc[f + 4], bnsh[f + 4]), 0.f);
    a5 = fmaxf(fmaf(a5, bnsc[f + 5], bnsh[f + 5]), 0.f);
    a6 = fmaxf(fmaf(a6, bnsc[f + 6], bnsh[f + 6]), 0.f);
    a7 = fmaxf(fmaf(a7, bnsc[f + 7], bnsh[f + 7]), 0.f);
    if (lane < 16) {
      uint4 p;
      p.x = (unsigned)f2bf(a0) | ((unsigned)f2bf(a1) << 16);
      p.y = (unsigned)f2bf(a2) | ((unsigned)f2bf(a3) << 16);
      p.z = (unsigned)f2bf(a4) | ((unsigned)f2bf(a5) << 16);
      p.w = (unsigned)f2bf(a6) | ((unsigned)f2bf(a7) << 16);
      ((uint4*)outp)[(size_t)wid * 16 + li] = p;
    }
  } else {
    const int li = lane & 7;    // uint4 index: features 8*li .. 8*li+7
    const int es = lane >> 3;   // edge slot (0..7)
    int e = start;
    for (; e + 15 < end; e += 16) {
      unsigned int c0 = csr4[e + es], c1 = csr4[e + 8 + es];
      uint4 u0 = ((const uint4*)(xwb + (size_t)c4row(c0) * 32))[li];
      uint4 u1 = ((const uint4*)(xwb + (size_t)c4row(c1) * 32))[li];
      ACC8(u0, c4w(c0)); ACC8(u1, c4w(c1));
    }
    for (; e + 7 < end; e += 8) {
      unsigned int c0 = csr4[e + es];
      uint4 u0 = ((const uint4*)(xwb + (size_t)c4row(c0) * 32))[li];
      ACC8(u0, c4w(c0));
    }
    for (; e < end; ++e) {
      unsigned int c0 = csr4[e];
      uint4 u0 = ((const uint4*)(xwb + (size_t)c4row(c0) * 32))[li];
      float n0 = (es == 0) ? c4w(c0) : 0.f;
      ACC8(u0, n0);
    }
    // reduce the eight edge slots
    a0 += __shfl_xor(a0, 8);  a1 += __shfl_xor(a1, 8);
    a2 += __shfl_xor(a2, 8);  a3 += __shfl_xor(a3, 8);
    a4 += __shfl_xor(a4, 8);  a5 += __shfl_xor(a5, 8);
    a6 += __shfl_xor(a6, 8);  a7 += __shfl_xor(a7, 8);
    a0 += __shfl_xor(a0, 16); a1 += __shfl_xor(a1, 16);
    a2 += __shfl_xor(a2, 16); a3 += __shfl_xor(a3, 16);
    a4 += __shfl_xor(a4, 16); a5 += __shfl_xor(a5, 16);
    a6 += __shfl_xor(a6, 16); a7 += __shfl_xor(a7, 16);
    a0 += __shfl_xor(a0, 32); a1 += __shfl_xor(a1, 32);
    a2 += __shfl_xor(a2, 32); a3 += __shfl_xor(a3, 32);
    a4 += __shfl_xor(a4, 32); a5 += __shfl_xor(a5, 32);
    a6 += __shfl_xor(a6, 32); a7 += __shfl_xor(a7, 32);
    // self + dinv + bias
    uint4 su = ((const uint4*)(xwb + (size_t)wid * 32))[li];
    a0 += bflo(su.x); a1 += bfhi(su.x); a2 += bflo(su.y); a3 += bfhi(su.y);
    a4 += bflo(su.z); a5 += bfhi(su.z); a6 += bflo(su.w); a7 += bfhi(su.w);
    const int f = li * 8;
    a0 = fmaf(dv, a0, bias[f]);     a1 = fmaf(dv, a1, bias[f + 1]);
    a2 = fmaf(dv, a2, bias[f + 2]); a3 = fmaf(dv, a3, bias[f + 3]);
    a4 = fmaf(dv, a4, bias[f + 4]); a5 = fmaf(dv, a5, bias[f + 5]);
    a6 = fmaf(dv, a6, bias[f + 6]); a7 = fmaf(dv, a7, bias[f + 7]);
    // L2 norm across the 8-lane feature group
    float s = a0 * a0 + a1 * a1 + a2 * a2 + a3 * a3
            + a4 * a4 + a5 * a5 + a6 * a6 + a7 * a7;
#pragma unroll
    for (int off = 4; off >= 1; off >>= 1) s += __shfl_xor(s, off);
    float scale = 1.0f / fmaxf(sqrtf(s), 1e-12f);
    if (lane < 8) {
      float* op = (float*)outp + (size_t)wid * 64 + f;
      float4 o0 = make_float4(a0 * scale, a1 * scale, a2 * scale, a3 * scale);
      float4 o1 = make_float4(a4 * scale, a5 * scale, a6 * scale, a7 * scale);
      *(float4*)(op)     = o0;
      *(float4*)(op + 4) = o1;
    }
  }
}

extern "C" void kernel_launch(void* const* d_in, const int* in_sizes, int n_in,
                              void* d_out, int out_size, void* d_ws, size_t ws_size,
                              hipStream_t stream)
{
  const float* x   = (const float*)d_in[0];
  const int*   ei  = (const int*)d_in[1];
  const float* ew  = (const float*)d_in[2];
  const float* W1  = (const float*)d_in[3];
  const float* b1  = (const float*)d_in[4];
  const float* g1  = (const float*)d_in[5];
  const float* be1 = (const float*)d_in[6];
  const float* rm1 = (const float*)d_in[7];
  const float* rv1 = (const float*)d_in[8];
  const float* W2  = (const float*)d_in[9];
  const float* b2  = (const float*)d_in[10];
  const float* g2  = (const float*)d_in[11];
  const float* be2 = (const float*)d_in[12];
  const float* rm2 = (const float*)d_in[13];
  const float* rv2 = (const float*)d_in[14];
  const float* W3  = (const float*)d_in[15];
  const float* b3  = (const float*)d_in[16];

  const int N = in_sizes[0] / 128;
  const int E = in_sizes[2];
  const int* row = ei;       // edge_index[0]
  const int* col = ei + E;   // edge_index[1]

  const int nbk   = (N + 255) >> 8;                 // coarse buckets (col>>8)
  const int nblkA = (E + AB_CHUNK - 1) / AB_CHUNK;  // phase-A blocks
  const int L     = nbk * nblkA;                    // count-matrix length
  const int nb2   = (L + 1023) / 1024;              // scan partial blocks

  char* ws = (char*)d_ws;
  size_t off = 0;
  auto alloc = [&](size_t bytes) -> void* {
    void* p = ws + off;
    off += (bytes + 255) & ~(size_t)255;
    return p;
  };
  int*   cntmat = (int*)  alloc((size_t)L * 4);
  int*   scnt   = (int*)  alloc((size_t)(L + 1) * 4);
  int*   bsum   = (int*)  alloc((size_t)1024 * 4);
  int2*  bucketed = (int2*)alloc((size_t)E * 8);
  unsigned int* csr4 = (unsigned int*)alloc((size_t)E * 4);
  int*   rowptr = (int*)  alloc((size_t)(N + 1) * 4);
  float* dinv   = (float*)alloc((size_t)N * 4);
  float* sc1    = (float*)alloc(512);
  float* sh1    = (float*)alloc(512);
  float* sc2    = (float*)alloc(512);
  float* sh2    = (float*)alloc(512);
  unsigned short* Wt1 = (unsigned short*)alloc(128 * 128 * 2);
  unsigned short* Wt2 = (unsigned short*)alloc(128 * 128 * 2);
  unsigned short* Wt3 = (unsigned short*)alloc(64 * 128 * 2);
  unsigned int* xwb = (unsigned int*)alloc((size_t)N * 64 * 4);  // bf16-packed y
  unsigned int* hb  = (unsigned int*)alloc((size_t)N * 64 * 4);  // bf16-packed h

  // ---- weight transposes + BN prep ----
  wt3_kernel<<<160, 256, 0, stream>>>(W1, W2, W3, Wt1, Wt2, Wt3);
  bn_prep_kernel<<<1, 128, 0, stream>>>(g1, be1, rm1, rv1, g2, be2, rm2, rv2,
                                        sc1, sh1, sc2, sh2);

  // ---- CSR build (deterministic two-level bucket sort) ----
  histA<<<nblkA, 256, 0, stream>>>(col, cntmat, E, nbk, nblkA);
  scan_partial<<<nb2, 256, 0, stream>>>(cntmat, bsum, L);
  scan_bsum<<<1, 1024, 0, stream>>>(bsum, nb2, scnt, L);
  scan_apply<<<nb2, 256, 0, stream>>>(cntmat, bsum, scnt, L);
  scatA<<<nblkA, 256, 0, stream>>>(row, col, ew, scnt, bucketed, E, nbk, nblkA);
  bucketB<<<nbk, 256, 0, stream>>>(bucketed, scnt, csr4, rowptr, dinv, E, N, nbk, nblkA);

  const int gGM = (N + 63) / 64;  // mfma gemm blocks (64 rows each)
  const int gW  = (N + 3) / 4;    // gather blocks (4 waves/block)

  // layer 1
  gemm_mfma<128, false><<<gGM, 256, 0, stream>>>(x, Wt1, dinv, xwb, N);
  gather_kernel<0><<<gW, 256, 0, stream>>>(rowptr, csr4, xwb, dinv, b1, sc1, sh1, hb, N);

  // layer 2
  gemm_mfma<128, true><<<gGM, 256, 0, stream>>>(hb, Wt2, dinv, xwb, N);
  gather_kernel<0><<<gW, 256, 0, stream>>>(rowptr, csr4, xwb, dinv, b2, sc2, sh2, hb, N);

  // layer 3 (DOUT=64) + fused L2 normalize -> d_out
  gemm_mfma<64, true><<<gGM, 256, 0, stream>>>(hb, Wt3, dinv, xwb, N);
  gather_kernel<1><<<gW, 256, 0, stream>>>(rowptr, csr4, xwb, dinv, b3, nullptr, nullptr,
                                           (float*)d_out, N);
}

// Round 11
// 311.895 us; speedup vs baseline: 2.4995x; 1.0573x over previous
//
#include <hip/hip_runtime.h>
#include <cstddef>

#define TPB 256
#define AB_CHUNK 4096   // edges per phase-A block

typedef __attribute__((ext_vector_type(8))) short short8;   // 8 bf16 (4 VGPRs)
typedef __attribute__((ext_vector_type(4))) float f32x4;    // MFMA C/D frag

__device__ inline unsigned short f2bf(float f) {  // RNE float->bf16
  unsigned int u = __float_as_uint(f);
  return (unsigned short)((u + 0x7fffu + ((u >> 16) & 1u)) >> 16);
}
__device__ inline float bflo(unsigned int u) { return __uint_as_float(u << 16); }
__device__ inline float bfhi(unsigned int u) { return __uint_as_float(u & 0xffff0000u); }

// decode csr4 entry: row(17 bits, <<15) | top-15-bits-of-bf16(w)
__device__ inline int   c4row(unsigned int c) { return (int)(c >> 15); }
__device__ inline float c4w(unsigned int c)   { return __uint_as_float((c & 0x7fffu) << 16); }

// ---- Phase A1: per-block coarse histogram (bucket = col>>8), LDS atomics only
__global__ __launch_bounds__(256) void histA(const int* __restrict__ col,
                                             int* __restrict__ cntmat,
                                             int E, int nbk, int nblkA) {
  __shared__ int hist[512];
  for (int i = threadIdx.x; i < nbk; i += 256) hist[i] = 0;
  __syncthreads();
  const int base = blockIdx.x * AB_CHUNK;
  const int lim  = min(base + AB_CHUNK, E);
  for (int i = base + threadIdx.x; i < lim; i += 256)
    atomicAdd(&hist[col[i] >> 8], 1);
  __syncthreads();
  for (int k = threadIdx.x; k < nbk; k += 256)
    cntmat[k * nblkA + blockIdx.x] = hist[k];   // bucket-major
}

// ---- hierarchical exclusive scan (arbitrary n; out[n] = total) ----
__global__ __launch_bounds__(256) void scan_partial(const int* __restrict__ cnt,
                                                    int* __restrict__ bsum, int n) {
  __shared__ int red[256];
  const int b = blockIdx.x, tid = threadIdx.x;
  const int base = b * 1024 + tid * 4;
  int s = 0;
  if (base + 3 < n) {
    int4 v = *(const int4*)(cnt + base);
    s = v.x + v.y + v.z + v.w;
  } else {
    for (int j = 0; j < 4; ++j) if (base + j < n) s += cnt[base + j];
  }
  red[tid] = s; __syncthreads();
  for (int off = 128; off >= 1; off >>= 1) {
    if (tid < off) red[tid] += red[tid + off];
    __syncthreads();
  }
  if (tid == 0) bsum[b] = red[0];
}

__global__ __launch_bounds__(1024) void scan_bsum(int* __restrict__ bsum, int nb,
                                                  int* __restrict__ out, int n) {
  __shared__ int sh[1024];
  const int tid = threadIdx.x;
  int v = (tid < nb) ? bsum[tid] : 0;
  sh[tid] = v; __syncthreads();
  for (int off = 1; off < 1024; off <<= 1) {
    int t = (tid >= off) ? sh[tid - off] : 0;
    __syncthreads();
    sh[tid] += t;
    __syncthreads();
  }
  if (tid < nb) bsum[tid] = sh[tid] - v;   // exclusive
  if (tid == 1023) out[n] = sh[1023];      // grand total
}

__global__ __launch_bounds__(256) void scan_apply(const int* __restrict__ cnt,
                                                  const int* __restrict__ bsum,
                                                  int* __restrict__ out, int n) {
  __shared__ int red[256];
  const int b = blockIdx.x, tid = threadIdx.x;
  const int base = b * 1024 + tid * 4;
  int v0 = 0, v1 = 0, v2 = 0, v3 = 0;
  if (base + 3 < n) {
    int4 v = *(const int4*)(cnt + base);
    v0 = v.x; v1 = v.y; v2 = v.z; v3 = v.w;
  } else {
    if (base     < n) v0 = cnt[base];
    if (base + 1 < n) v1 = cnt[base + 1];
    if (base + 2 < n) v2 = cnt[base + 2];
    if (base + 3 < n) v3 = cnt[base + 3];
  }
  const int t = v0 + v1 + v2 + v3;
  red[tid] = t; __syncthreads();
  for (int off = 1; off < 256; off <<= 1) {
    int x = (tid >= off) ? red[tid - off] : 0;
    __syncthreads();
    red[tid] += x;
    __syncthreads();
  }
  int excl = red[tid] - t + bsum[b];
  if (base     < n) out[base]     = excl;
  if (base + 1 < n) out[base + 1] = excl + v0;
  if (base + 2 < n) out[base + 2] = excl + v0 + v1;
  if (base + 3 < n) out[base + 3] = excl + v0 + v1 + v2;
}

// ---- Phase A3: scatter edges into bucket-contiguous order
// payload: {row | (col&255)<<17, w_bits}  (row < 2^17, col_local < 256)
__global__ __launch_bounds__(256) void scatA(const int* __restrict__ row,
                                             const int* __restrict__ col,
                                             const float* __restrict__ w,
                                             const int* __restrict__ scnt,
                                             int2* __restrict__ bucketed,
                                             int E, int nbk, int nblkA) {
  __shared__ int cur[512];
  for (int k = threadIdx.x; k < nbk; k += 256)
    cur[k] = scnt[k * nblkA + blockIdx.x];
  __syncthreads();
  const int base = blockIdx.x * AB_CHUNK;
  const int lim  = min(base + AB_CHUNK, E);
  for (int i = base + threadIdx.x; i < lim; i += 256) {
    int c = col[i];
    int pos = atomicAdd(&cur[c >> 8], 1);
    bucketed[pos] = make_int2(row[i] | ((c & 255) << 17), __float_as_int(w[i]));
  }
}

// ---- Phase B: per-bucket (256 nodes) local sort -> csr4 + rowptr + dinv
__global__ __launch_bounds__(256) void bucketB(const int2* __restrict__ bucketed,
                                               const int* __restrict__ scnt,
                                               unsigned int* __restrict__ csr4,
                                               int* __restrict__ rowptr,
                                               float* __restrict__ dinv,
                                               int E, int N, int nbk, int nblkA) {
  __shared__ int   hist[256];   // then reused as cursor
  __shared__ float degf[256];
  __shared__ int   excl[256];
  const int b = blockIdx.x, tid = threadIdx.x;
  const int start = scnt[b * nblkA];
  const int end   = (b == nbk - 1) ? E : scnt[(b + 1) * nblkA];
  hist[tid] = 0; degf[tid] = 0.f;
  __syncthreads();
  for (int i = start + tid; i < end; i += 256) {
    int2 p = bucketed[i];
    int cl = (p.x >> 17) & 255;
    atomicAdd(&hist[cl], 1);
    atomicAdd(&degf[cl], __int_as_float(p.y));
  }
  __syncthreads();
  const int v = hist[tid];
  excl[tid] = v;
  __syncthreads();
  for (int off = 1; off < 256; off <<= 1) {
    int t = (tid >= off) ? excl[tid - off] : 0;
    __syncthreads();
    excl[tid] += t;
    __syncthreads();
  }
  const int ex = excl[tid] - v;  // exclusive prefix within bucket
  const int node = b * 256 + tid;
  if (node < N) {
    rowptr[node] = start + ex;
    dinv[node]   = rsqrtf(degf[tid] + 1.0f);   // +1 = self-loop
  }
  if (b == nbk - 1 && tid == 0) rowptr[N] = E;
  __syncthreads();
  hist[tid] = ex;       // reuse as running cursor
  __syncthreads();
  for (int i = start + tid; i < end; i += 256) {
    int2 p = bucketed[i];
    int cl = (p.x >> 17) & 255;
    int pos = start + atomicAdd(&hist[cl], 1);
    unsigned int wq = (unsigned int)f2bf(__int_as_float(p.y)) & 0x7fffu;
    csr4[pos] = ((unsigned int)(p.x & 0x1FFFF) << 15) | wq;   // {row, bf16 w}
  }
}

__global__ void bn_prep_kernel(const float* g1, const float* be1, const float* rm1, const float* rv1,
                               const float* g2, const float* be2, const float* rm2, const float* rv2,
                               float* sc1, float* sh1, float* sc2, float* sh2) {
  int t = threadIdx.x;
  if (t < 128) {
    float s1 = g1[t] * rsqrtf(rv1[t] + 1e-5f);
    sc1[t] = s1; sh1[t] = be1[t] - rm1[t] * s1;
    float s2 = g2[t] * rsqrtf(rv2[t] + 1e-5f);
    sc2[t] = s2; sh2[t] = be2[t] - rm2[t] * s2;
  }
}

// all three weight transposes in one launch: W[128,DOUT] f32 -> Wt[DOUT,128] bf16
__global__ void wt3_kernel(const float* __restrict__ W1, const float* __restrict__ W2,
                           const float* __restrict__ W3,
                           unsigned short* __restrict__ Wt1, unsigned short* __restrict__ Wt2,
                           unsigned short* __restrict__ Wt3) {
  int t = blockIdx.x * blockDim.x + threadIdx.x;
  if (t < 16384) {
    int nidx = t >> 7, k = t & 127;
    Wt1[t] = f2bf(W1[(size_t)k * 128 + nidx]);
  } else if (t < 32768) {
    int u = t - 16384; int nidx = u >> 7, k = u & 127;
    Wt2[u] = f2bf(W2[(size_t)k * 128 + nidx]);
  } else if (t < 40960) {
    int u = t - 32768; int nidx = u >> 7, k = u & 127;
    Wt3[u] = f2bf(W3[(size_t)k * 64 + nidx]);
  }
}

// MFMA GEMM: Xbf[64-row tile] @ W -> y = dinv[r]*(X@W) packed bf16 (ld = DOUT/2 uints)
template<int DOUT, bool BF16IN>
__global__ __launch_bounds__(256) void gemm_mfma(
    const void* Xin,                         // f32[N,128] or packed-bf16 uint[N,64]
    const unsigned short* __restrict__ Wt,   // bf16 [DOUT][128]
    const float* __restrict__ dinv,
    unsigned int* __restrict__ XWb, int n)
{
  constexpr int CT = DOUT / 16;
  __shared__ unsigned short Xs[64][136];     // +8 pad: 2-way banks (free)
  __shared__ unsigned short Ws[DOUT][136];
  const int tid = threadIdx.x;
  const int r0  = blockIdx.x * 64;

  if constexpr (BF16IN) {
    const unsigned int* hb = (const unsigned int*)Xin;
    for (int i = tid; i < 64 * 16; i += 256) {           // uint4 = 8 bf16
      int rr = i >> 4, q = i & 15;
      uint4 v = make_uint4(0, 0, 0, 0);
      if (r0 + rr < n) v = *(const uint4*)(hb + (size_t)(r0 + rr) * 64 + q * 4);
      *(uint4*)(&Xs[rr][q * 8]) = v;
    }
  } else {
    const float* X = (const float*)Xin;
    for (int i = tid; i < 64 * 32; i += 256) {           // float4 -> 4 bf16
      int rr = i >> 5, q = i & 31;
      float4 v = make_float4(0.f, 0.f, 0.f, 0.f);
      if (r0 + rr < n) v = *(const float4*)(X + (size_t)(r0 + rr) * 128 + q * 4);
      uint2 p;
      p.x = (unsigned)f2bf(v.x) | ((unsigned)f2bf(v.y) << 16);
      p.y = (unsigned)f2bf(v.z) | ((unsigned)f2bf(v.w) << 16);
      *(uint2*)(&Xs[rr][q * 4]) = p;
    }
  }
  for (int i = tid; i < DOUT * 16; i += 256) {
    int nr = i >> 4, q = i & 15;
    *(uint4*)(&Ws[nr][q * 8]) = *(const uint4*)(Wt + (size_t)nr * 128 + q * 8);
  }
  __syncthreads();

  const int wid  = tid >> 6, lane = tid & 63;
  const int arow = wid * 16 + (lane & 15);
  const int koff = (lane >> 4) << 3;

  short8 af[4];
#pragma unroll
  for (int s = 0; s < 4; ++s)
    af[s] = *(const short8*)(&Xs[arow][s * 32 + koff]);

  f32x4 acc[CT];
#pragma unroll
  for (int ct = 0; ct < CT; ++ct) acc[ct] = (f32x4){0.f, 0.f, 0.f, 0.f};

#pragma unroll
  for (int ct = 0; ct < CT; ++ct) {
    const int brow = ct * 16 + (lane & 15);
#pragma unroll
    for (int s = 0; s < 4; ++s) {
      short8 bf = *(const short8*)(&Ws[brow][s * 32 + koff]);
      acc[ct] = __builtin_amdgcn_mfma_f32_16x16x32_bf16(af[s], bf, acc[ct], 0, 0, 0);
    }
  }

  const int rbase = r0 + wid * 16 + ((lane >> 4) << 2);
  float dvv[4];
#pragma unroll
  for (int i = 0; i < 4; ++i) dvv[i] = (rbase + i < n) ? dinv[rbase + i] : 0.f;

#pragma unroll
  for (int ct = 0; ct < CT; ++ct) {
#pragma unroll
    for (int i = 0; i < 4; ++i) {
      float v = acc[ct][i] * dvv[i];
      float o = __shfl_xor(v, 1);   // partner col
      if (!(lane & 1) && rbase + i < n) {
        unsigned int p = (unsigned)f2bf(v) | ((unsigned)f2bf(o) << 16);
        XWb[(size_t)(rbase + i) * (DOUT / 2) + ct * 8 + ((lane & 15) >> 1)] = p;
      }
    }
  }
}

// unpack-accumulate a uint4 (8 bf16) scaled by nm into a0..a7
#define ACC8(u, nm)                                                   \
  a0 = fmaf(bflo((u).x), (nm), a0); a1 = fmaf(bfhi((u).x), (nm), a1); \
  a2 = fmaf(bflo((u).y), (nm), a2); a3 = fmaf(bfhi((u).y), (nm), a3); \
  a4 = fmaf(bflo((u).z), (nm), a4); a5 = fmaf(bfhi((u).z), (nm), a5); \
  a6 = fmaf(bflo((u).w), (nm), a6); a7 = fmaf(bfhi((u).w), (nm), a7);

// pull-gather from bf16 y: h = bias + dinv[i]*( y_i + sum_e w_e * y_{row_e} )
// MODE 0 (D=128): 16 lanes x uint4 per edge, 4 edge slots, 16 edges in flight;
//                 BN+ReLU fused, writes packed bf16.
// MODE 1 (D=64):  16 lanes x uint2 per edge, 4 edge slots, light epilogue
//                 (final layer is epilogue-dominated at deg~16);
//                 L2-normalize fused, writes f32 d_out.
template<int MODE>
__global__ __launch_bounds__(256) void gather_kernel(
    const int* __restrict__ rowptr, const unsigned int* __restrict__ csr4,
    const unsigned int* __restrict__ xwb, const float* __restrict__ dinv,
    const float* __restrict__ bias,
    const float* __restrict__ bnsc, const float* __restrict__ bnsh,
    void* __restrict__ outp, int n)
{
  int wid  = (blockIdx.x * blockDim.x + threadIdx.x) >> 6;
  int lane = threadIdx.x & 63;
  if (wid >= n) return;
  const int start = rowptr[wid];
  const int end   = rowptr[wid + 1];
  const float dv  = dinv[wid];
  float a0 = 0.f, a1 = 0.f, a2 = 0.f, a3 = 0.f;

  if constexpr (MODE == 0) {
    float a4 = 0.f, a5 = 0.f, a6 = 0.f, a7 = 0.f;
    const int li = lane & 15;   // uint4 index: features 8*li .. 8*li+7
    const int es = lane >> 4;   // edge slot (0..3)
    int e = start;
    for (; e + 15 < end; e += 16) {
      unsigned int c0 = csr4[e      + es], c1 = csr4[e + 4  + es];
      unsigned int c2 = csr4[e + 8  + es], c3 = csr4[e + 12 + es];
      uint4 u0 = ((const uint4*)(xwb + (size_t)c4row(c0) * 64))[li];
      uint4 u1 = ((const uint4*)(xwb + (size_t)c4row(c1) * 64))[li];
      uint4 u2 = ((const uint4*)(xwb + (size_t)c4row(c2) * 64))[li];
      uint4 u3 = ((const uint4*)(xwb + (size_t)c4row(c3) * 64))[li];
      float n0 = c4w(c0), n1 = c4w(c1), n2 = c4w(c2), n3 = c4w(c3);
      ACC8(u0, n0); ACC8(u1, n1); ACC8(u2, n2); ACC8(u3, n3);
    }
    for (; e + 3 < end; e += 4) {
      unsigned int c0 = csr4[e + es];
      uint4 u0 = ((const uint4*)(xwb + (size_t)c4row(c0) * 64))[li];
      ACC8(u0, c4w(c0));
    }
    for (; e < end; ++e) {
      unsigned int c0 = csr4[e];
      uint4 u0 = ((const uint4*)(xwb + (size_t)c4row(c0) * 64))[li];
      float n0 = (es == 0) ? c4w(c0) : 0.f;
      ACC8(u0, n0);
    }
    // reduce the four edge slots
    a0 += __shfl_xor(a0, 16); a1 += __shfl_xor(a1, 16);
    a2 += __shfl_xor(a2, 16); a3 += __shfl_xor(a3, 16);
    a4 += __shfl_xor(a4, 16); a5 += __shfl_xor(a5, 16);
    a6 += __shfl_xor(a6, 16); a7 += __shfl_xor(a7, 16);
    a0 += __shfl_xor(a0, 32); a1 += __shfl_xor(a1, 32);
    a2 += __shfl_xor(a2, 32); a3 += __shfl_xor(a3, 32);
    a4 += __shfl_xor(a4, 32); a5 += __shfl_xor(a5, 32);
    a6 += __shfl_xor(a6, 32); a7 += __shfl_xor(a7, 32);
    // self + dinv + bias + BN + ReLU
    uint4 su = ((const uint4*)(xwb + (size_t)wid * 64))[li];
    a0 += bflo(su.x); a1 += bfhi(su.x); a2 += bflo(su.y); a3 += bfhi(su.y);
    a4 += bflo(su.z); a5 += bfhi(su.z); a6 += bflo(su.w); a7 += bfhi(su.w);
    const int f = li * 8;
    a0 = fmaf(dv, a0, bias[f]);     a1 = fmaf(dv, a1, bias[f + 1]);
    a2 = fmaf(dv, a2, bias[f + 2]); a3 = fmaf(dv, a3, bias[f + 3]);
    a4 = fmaf(dv, a4, bias[f + 4]); a5 = fmaf(dv, a5, bias[f + 5]);
    a6 = fmaf(dv, a6, bias[f + 6]); a7 = fmaf(dv, a7, bias[f + 7]);
    a0 = fmaxf(fmaf(a0, bnsc[f],     bnsh[f]),     0.f);
    a1 = fmaxf(fmaf(a1, bnsc[f + 1], bnsh[f + 1]), 0.f);
    a2 = fmaxf(fmaf(a2, bnsc[f + 2], bnsh[f + 2]), 0.f);
    a3 = fmaxf(fmaf(a3, bnsc[f + 3], bnsh[f + 3]), 0.f);
    a4 = fmaxf(fmaf(a4, bnsc[f + 4], bnsh[f + 4]), 0.f);
    a5 = fmaxf(fmaf(a5, bnsc[f + 5], bnsh[f + 5]), 0.f);
    a6 = fmaxf(fmaf(a6, bnsc[f + 6], bnsh[f + 6]), 0.f);
    a7 = fmaxf(fmaf(a7, bnsc[f + 7], bnsh[f + 7]), 0.f);
    if (lane < 16) {
      uint4 p;
      p.x = (unsigned)f2bf(a0) | ((unsigned)f2bf(a1) << 16);
      p.y = (unsigned)f2bf(a2) | ((unsigned)f2bf(a3) << 16);
      p.z = (unsigned)f2bf(a4) | ((unsigned)f2bf(a5) << 16);
      p.w = (unsigned)f2bf(a6) | ((unsigned)f2bf(a7) << 16);
      ((uint4*)outp)[(size_t)wid * 16 + li] = p;
    }
  } else {
    // D=64 (32 uints/row): 16 lanes x uint2 per edge, 4 edge slots
    const int li = lane & 15;   // uint2 index: features 4*li .. 4*li+3
    const int es = lane >> 4;   // edge slot (0..3)
    int e = start;
    for (; e + 7 < end; e += 8) {
      unsigned int c0 = csr4[e + es], c1 = csr4[e + 4 + es];
      uint2 u0 = ((const uint2*)(xwb + (size_t)c4row(c0) * 32))[li];
      uint2 u1 = ((const uint2*)(xwb + (size_t)c4row(c1) * 32))[li];
      float n0 = c4w(c0), n1 = c4w(c1);
      a0 = fmaf(bflo(u0.x), n0, a0); a1 = fmaf(bfhi(u0.x), n0, a1);
      a2 = fmaf(bflo(u0.y), n0, a2); a3 = fmaf(bfhi(u0.y), n0, a3);
      a0 = fmaf(bflo(u1.x), n1, a0); a1 = fmaf(bfhi(u1.x), n1, a1);
      a2 = fmaf(bflo(u1.y), n1, a2); a3 = fmaf(bfhi(u1.y), n1, a3);
    }
    for (; e < end; e += 4) {       // masked tail (<8 edges left)
      int idx = e + es;
      bool valid = idx < end;
      unsigned int c0 = csr4[valid ? idx : start];
      float n0 = valid ? c4w(c0) : 0.f;
      uint2 u0 = ((const uint2*)(xwb + (size_t)c4row(c0) * 32))[li];
      a0 = fmaf(bflo(u0.x), n0, a0); a1 = fmaf(bfhi(u0.x), n0, a1);
      a2 = fmaf(bflo(u0.y), n0, a2); a3 = fmaf(bfhi(u0.y), n0, a3);
    }
    // reduce the four edge slots
    a0 += __shfl_xor(a0, 16); a1 += __shfl_xor(a1, 16);
    a2 += __shfl_xor(a2, 16); a3 += __shfl_xor(a3, 16);
    a0 += __shfl_xor(a0, 32); a1 += __shfl_xor(a1, 32);
    a2 += __shfl_xor(a2, 32); a3 += __shfl_xor(a3, 32);
    // self + dinv + bias
    uint2 su = ((const uint2*)(xwb + (size_t)wid * 32))[li];
    a0 += bflo(su.x); a1 += bfhi(su.x); a2 += bflo(su.y); a3 += bfhi(su.y);
    const int f = li * 4;
    a0 = fmaf(dv, a0, bias[f]);     a1 = fmaf(dv, a1, bias[f + 1]);
    a2 = fmaf(dv, a2, bias[f + 2]); a3 = fmaf(dv, a3, bias[f + 3]);
    // L2 norm across the 16-lane feature group
    float s = a0 * a0 + a1 * a1 + a2 * a2 + a3 * a3;
    s += __shfl_xor(s, 8); s += __shfl_xor(s, 4);
    s += __shfl_xor(s, 2); s += __shfl_xor(s, 1);
    float scale = 1.0f / fmaxf(sqrtf(s), 1e-12f);
    if (lane < 16) {
      float4 o = make_float4(a0 * scale, a1 * scale, a2 * scale, a3 * scale);
      *(float4*)((float*)outp + (size_t)wid * 64 + f) = o;
    }
  }
}

extern "C" void kernel_launch(void* const* d_in, const int* in_sizes, int n_in,
                              void* d_out, int out_size, void* d_ws, size_t ws_size,
                              hipStream_t stream)
{
  const float* x   = (const float*)d_in[0];
  const int*   ei  = (const int*)d_in[1];
  const float* ew  = (const float*)d_in[2];
  const float* W1  = (const float*)d_in[3];
  const float* b1  = (const float*)d_in[4];
  const float* g1  = (const float*)d_in[5];
  const float* be1 = (const float*)d_in[6];
  const float* rm1 = (const float*)d_in[7];
  const float* rv1 = (const float*)d_in[8];
  const float* W2  = (const float*)d_in[9];
  const float* b2  = (const float*)d_in[10];
  const float* g2  = (const float*)d_in[11];
  const float* be2 = (const float*)d_in[12];
  const float* rm2 = (const float*)d_in[13];
  const float* rv2 = (const float*)d_in[14];
  const float* W3  = (const float*)d_in[15];
  const float* b3  = (const float*)d_in[16];

  const int N = in_sizes[0] / 128;
  const int E = in_sizes[2];
  const int* row = ei;       // edge_index[0]
  const int* col = ei + E;   // edge_index[1]

  const int nbk   = (N + 255) >> 8;                 // coarse buckets (col>>8)
  const int nblkA = (E + AB_CHUNK - 1) / AB_CHUNK;  // phase-A blocks
  const int L     = nbk * nblkA;                    // count-matrix length
  const int nb2   = (L + 1023) / 1024;              // scan partial blocks

  char* ws = (char*)d_ws;
  size_t off = 0;
  auto alloc = [&](size_t bytes) -> void* {
    void* p = ws + off;
    off += (bytes + 255) & ~(size_t)255;
    return p;
  };
  int*   cntmat = (int*)  alloc((size_t)L * 4);
  int*   scnt   = (int*)  alloc((size_t)(L + 1) * 4);
  int*   bsum   = (int*)  alloc((size_t)1024 * 4);
  int2*  bucketed = (int2*)alloc((size_t)E * 8);
  unsigned int* csr4 = (unsigned int*)alloc((size_t)E * 4);
  int*   rowptr = (int*)  alloc((size_t)(N + 1) * 4);
  float* dinv   = (float*)alloc((size_t)N * 4);
  float* sc1    = (float*)alloc(512);
  float* sh1    = (float*)alloc(512);
  float* sc2    = (float*)alloc(512);
  float* sh2    = (float*)alloc(512);
  unsigned short* Wt1 = (unsigned short*)alloc(128 * 128 * 2);
  unsigned short* Wt2 = (unsigned short*)alloc(128 * 128 * 2);
  unsigned short* Wt3 = (unsigned short*)alloc(64 * 128 * 2);
  unsigned int* xwb = (unsigned int*)alloc((size_t)N * 64 * 4);  // bf16-packed y
  unsigned int* hb  = (unsigned int*)alloc((size_t)N * 64 * 4);  // bf16-packed h

  // ---- weight transposes + BN prep ----
  wt3_kernel<<<160, 256, 0, stream>>>(W1, W2, W3, Wt1, Wt2, Wt3);
  bn_prep_kernel<<<1, 128, 0, stream>>>(g1, be1, rm1, rv1, g2, be2, rm2, rv2,
                                        sc1, sh1, sc2, sh2);

  // ---- CSR build (deterministic two-level bucket sort) ----
  histA<<<nblkA, 256, 0, stream>>>(col, cntmat, E, nbk, nblkA);
  scan_partial<<<nb2, 256, 0, stream>>>(cntmat, bsum, L);
  scan_bsum<<<1, 1024, 0, stream>>>(bsum, nb2, scnt, L);
  scan_apply<<<nb2, 256, 0, stream>>>(cntmat, bsum, scnt, L);
  scatA<<<nblkA, 256, 0, stream>>>(row, col, ew, scnt, bucketed, E, nbk, nblkA);
  bucketB<<<nbk, 256, 0, stream>>>(bucketed, scnt, csr4, rowptr, dinv, E, N, nbk, nblkA);

  const int gGM = (N + 63) / 64;  // mfma gemm blocks (64 rows each)
  const int gW  = (N + 3) / 4;    // gather blocks (4 waves/block)

  // layer 1
  gemm_mfma<128, false><<<gGM, 256, 0, stream>>>(x, Wt1, dinv, xwb, N);
  gather_kernel<0><<<gW, 256, 0, stream>>>(rowptr, csr4, xwb, dinv, b1, sc1, sh1, hb, N);

  // layer 2
  gemm_mfma<128, true><<<gGM, 256, 0, stream>>>(hb, Wt2, dinv, xwb, N);
  gather_kernel<0><<<gW, 256, 0, stream>>>(rowptr, csr4, xwb, dinv, b2, sc2, sh2, hb, N);

  // layer 3 (DOUT=64) + fused L2 normalize -> d_out
  gemm_mfma<64, true><<<gGM, 256, 0, stream>>>(hb, Wt3, dinv, xwb, N);
  gather_kernel<1><<<gW, 256, 0, stream>>>(rowptr, csr4, xwb, dinv, b3, nullptr, nullptr,
                                           (float*)d_out, N);
}